// Round 1
// baseline (1957.689 us; speedup 1.0000x reference)
//
#include <hip/hip_runtime.h>
#include <math.h>

// Problem constants
// B=2, L=2048, E=1024, H=16, D=64
#define BQ 2
#define LQ 2048
#define EQ 1024
#define HQ 16
#define DQ 64
#define M_ROWS (BQ*LQ)          // 4096
#define BH (BQ*HQ)              // 32

// ---------------------------------------------------------------------------
// Tiled fp32 GEMM: C = A(MxK) @ W(KxN) + bias, K=1024 fixed, M=4096 fixed.
// mode 0: t-proj  N=3072 -> scatter qt->qcat[:,0:64], kt->kcat[:,0:64], vt->v
// mode 1: s-proj  N=2048 -> scatter qs->qcat[:,64:128], ks->kcat[:,64:128]
// mode 2: plain   N=1024 -> out0[row*N+col]
// Tile 128x128, BK=16, 256 threads, 8x8 per thread.
// ---------------------------------------------------------------------------
__global__ __launch_bounds__(256) void gemm_proj(
    const float* __restrict__ A, const float* __restrict__ W,
    const float* __restrict__ bias,
    float* __restrict__ out0, float* __restrict__ out1, float* __restrict__ out2,
    int N, int mode) {

  __shared__ float As[16][132];   // As[k][m] (transposed)
  __shared__ float Bs[16][132];   // Bs[k][n]

  const int tid = threadIdx.x;
  const int tx = tid & 15;        // col group
  const int ty = tid >> 4;        // row group
  const int m0 = blockIdx.y * 128;
  const int n0 = blockIdx.x * 128;

  float acc[8][8];
#pragma unroll
  for (int i = 0; i < 8; ++i)
#pragma unroll
    for (int j = 0; j < 8; ++j) acc[i][j] = 0.f;

  for (int kt = 0; kt < 1024; kt += 16) {
    // Load A tile: 128 rows x 16 k  (512 float4, 2 per thread), transpose to As[k][m]
#pragma unroll
    for (int p = 0; p < 2; ++p) {
      int idx = tid + p * 256;          // 0..511
      int row = idx >> 2;               // 0..127
      int k4 = (idx & 3) * 4;           // 0,4,8,12
      float4 av = *(const float4*)&A[(size_t)(m0 + row) * 1024 + kt + k4];
      As[k4 + 0][row] = av.x;
      As[k4 + 1][row] = av.y;
      As[k4 + 2][row] = av.z;
      As[k4 + 3][row] = av.w;
    }
    // Load B tile: 16 k-rows x 128 cols (512 float4, 2 per thread)
#pragma unroll
    for (int p = 0; p < 2; ++p) {
      int idx = tid + p * 256;
      int row = idx >> 5;               // 0..15
      int c4 = (idx & 31) * 4;          // 0..124
      *(float4*)&Bs[row][c4] = *(const float4*)&W[(size_t)(kt + row) * N + n0 + c4];
    }
    __syncthreads();

#pragma unroll
    for (int k = 0; k < 16; ++k) {
      float a[8], b[8];
      *(float4*)&a[0] = *(const float4*)&As[k][ty * 8];
      *(float4*)&a[4] = *(const float4*)&As[k][ty * 8 + 4];
      *(float4*)&b[0] = *(const float4*)&Bs[k][tx * 8];
      *(float4*)&b[4] = *(const float4*)&Bs[k][tx * 8 + 4];
#pragma unroll
      for (int i = 0; i < 8; ++i)
#pragma unroll
        for (int j = 0; j < 8; ++j)
          acc[i][j] = fmaf(a[i], b[j], acc[i][j]);
    }
    __syncthreads();
  }

  // Epilogue
  if (mode == 2) {
#pragma unroll
    for (int i = 0; i < 8; ++i) {
      int row = m0 + ty * 8 + i;
#pragma unroll
      for (int j = 0; j < 8; ++j) {
        int col = n0 + tx * 8 + j;
        out0[(size_t)row * N + col] = acc[i][j] + bias[col];
      }
    }
  } else {
#pragma unroll
    for (int i = 0; i < 8; ++i) {
      int row = m0 + ty * 8 + i;
      int bb = row >> 11;       // / 2048
      int ll = row & 2047;
#pragma unroll
      for (int j = 0; j < 8; ++j) {
        int col = n0 + tx * 8 + j;
        float val = acc[i][j] + bias[col];
        int which = col >> 10;
        int e = col & 1023;
        int hh = e >> 6;
        int dd = e & 63;
        size_t rowhd = (size_t)(bb * 16 + hh) * 2048 + ll;
        if (mode == 0) {
          if (which == 0)      out0[rowhd * 128 + dd] = val;          // qt
          else if (which == 1) out1[rowhd * 128 + dd] = val;          // kt
          else                 out2[rowhd * 64 + dd] = val;           // vt
        } else {
          if (which == 0)      out0[rowhd * 128 + 64 + dd] = val;     // qs
          else                 out1[rowhd * 128 + 64 + dd] = val;     // ks
        }
      }
    }
  }
}

// ---------------------------------------------------------------------------
// Combine: kcat[:,0:64]=kt, kcat[:,64:128]=ks  ->  k1 = kt + lts*ks,
//          k2 = lst*kt + lss*ks.  Also scale qcat by 1/sqrt(64)=0.125.
// One thread per (row, 4-dim group):  BH*L rows * 16 groups = 1,048,576 thr.
// ---------------------------------------------------------------------------
__global__ __launch_bounds__(256) void combine_kernel(
    float* __restrict__ qcat, float* __restrict__ kcat,
    const float* __restrict__ lam_ts, const float* __restrict__ lam_st,
    const float* __restrict__ lam_ss) {
  int idx = blockIdx.x * 256 + threadIdx.x;   // 0 .. 1048575
  int row = idx >> 4;
  int d4 = (idx & 15) * 4;
  float lts = lam_ts[0], lst = lam_st[0], lss = lam_ss[0];
  size_t base = (size_t)row * 128;

  float4 kt = *(float4*)&kcat[base + d4];
  float4 ks = *(float4*)&kcat[base + 64 + d4];
  float4 k1, k2;
  k1.x = kt.x + lts * ks.x;  k1.y = kt.y + lts * ks.y;
  k1.z = kt.z + lts * ks.z;  k1.w = kt.w + lts * ks.w;
  k2.x = lst * kt.x + lss * ks.x;  k2.y = lst * kt.y + lss * ks.y;
  k2.z = lst * kt.z + lss * ks.z;  k2.w = lst * kt.w + lss * ks.w;
  *(float4*)&kcat[base + d4] = k1;
  *(float4*)&kcat[base + 64 + d4] = k2;

  float4 q1 = *(float4*)&qcat[base + d4];
  float4 q2 = *(float4*)&qcat[base + 64 + d4];
  q1.x *= 0.125f; q1.y *= 0.125f; q1.z *= 0.125f; q1.w *= 0.125f;
  q2.x *= 0.125f; q2.y *= 0.125f; q2.z *= 0.125f; q2.w *= 0.125f;
  *(float4*)&qcat[base + d4] = q1;
  *(float4*)&qcat[base + 64 + d4] = q2;
}

// ---------------------------------------------------------------------------
// Flash attention: per (bh, 64-row q-tile). Concat-dim 128 scores, value dim 64.
// K-tiles of 32 keys, online softmax, O accumulated in registers.
// Thread layout 16x16: thread (ty,tx) owns S rows ty*4..+3, S cols tx*2..+1,
// O cols tx*4..+3.
// LDS: Qs 64x132 (33.0KB) + KP 32x132 (16.5KB, reused for P 64x36) + Vs 32x68
// (8.5KB) = 59,392 B.
// ---------------------------------------------------------------------------
__global__ __launch_bounds__(256) void flash_attn(
    const float* __restrict__ qcat, const float* __restrict__ kcat,
    const float* __restrict__ v, float* __restrict__ y) {
  const int bh = blockIdx.y;                 // 0..31
  const int qt0 = blockIdx.x * 64;
  const int b = bh >> 4, h = bh & 15;
  const float* Qg = qcat + (size_t)bh * LQ * 128 + (size_t)qt0 * 128;
  const float* Kg = kcat + (size_t)bh * LQ * 128;
  const float* Vg = v + (size_t)bh * LQ * 64;

  __shared__ float Qs[64][132];
  __shared__ float KP[32 * 132];             // K tile; reused as P (64x36)
  __shared__ float Vs[32][68];

  const int tid = threadIdx.x;
  const int tx = tid & 15;
  const int ty = tid >> 4;
  const int r0 = ty * 4;
  const int c0 = tx * 2;
  const int oc0 = tx * 4;

  // Load Q tile (64x128 = 2048 float4, 8 per thread)
#pragma unroll
  for (int p = 0; p < 8; ++p) {
    int idx = tid + p * 256;
    int row = idx >> 5;
    int c4 = (idx & 31) * 4;
    *(float4*)&Qs[row][c4] = *(const float4*)&Qg[(size_t)row * 128 + c4];
  }

  float m_i[4], l_i[4], acc_o[4][4];
#pragma unroll
  for (int i = 0; i < 4; ++i) {
    m_i[i] = -INFINITY;
    l_i[i] = 0.f;
#pragma unroll
    for (int j = 0; j < 4; ++j) acc_o[i][j] = 0.f;
  }

  for (int t = 0; t < LQ; t += 32) {
    __syncthreads();   // protect KP/Vs from previous-iter readers (also fences Q load)
    // Load K tile (32x128 = 1024 float4, 4 per thread)
#pragma unroll
    for (int p = 0; p < 4; ++p) {
      int idx = tid + p * 256;
      int row = idx >> 5;
      int c4 = (idx & 31) * 4;
      *(float4*)&KP[row * 132 + c4] = *(const float4*)&Kg[(size_t)(t + row) * 128 + c4];
    }
    // Load V tile (32x64 = 512 float4, 2 per thread)
#pragma unroll
    for (int p = 0; p < 2; ++p) {
      int idx = tid + p * 256;
      int row = idx >> 4;
      int c4 = (idx & 15) * 4;
      *(float4*)&Vs[row][c4] = *(const float4*)&Vg[(size_t)(t + row) * 64 + c4];
    }
    __syncthreads();

    // S = Q @ K^T over concat-dim 128
    float acc_s[4][2];
#pragma unroll
    for (int i = 0; i < 4; ++i) { acc_s[i][0] = 0.f; acc_s[i][1] = 0.f; }
#pragma unroll 8
    for (int k4 = 0; k4 < 32; ++k4) {
      float4 b0 = *(const float4*)&KP[(c0 + 0) * 132 + k4 * 4];
      float4 b1 = *(const float4*)&KP[(c0 + 1) * 132 + k4 * 4];
#pragma unroll
      for (int i = 0; i < 4; ++i) {
        float4 a = *(const float4*)&Qs[r0 + i][k4 * 4];
        acc_s[i][0] = fmaf(a.x, b0.x, fmaf(a.y, b0.y, fmaf(a.z, b0.z, fmaf(a.w, b0.w, acc_s[i][0]))));
        acc_s[i][1] = fmaf(a.x, b1.x, fmaf(a.y, b1.y, fmaf(a.z, b1.z, fmaf(a.w, b1.w, acc_s[i][1]))));
      }
    }

    // Online softmax (per q-row; 16 lanes per row-group reduce via shfl_xor)
    float p_ij[4][2];
#pragma unroll
    for (int i = 0; i < 4; ++i) {
      float mx = fmaxf(acc_s[i][0], acc_s[i][1]);
#pragma unroll
      for (int s = 1; s < 16; s <<= 1) mx = fmaxf(mx, __shfl_xor(mx, s));
      float m_new = fmaxf(m_i[i], mx);
      float alpha = __expf(m_i[i] - m_new);     // first iter: exp(-inf)=0
      float p0 = __expf(acc_s[i][0] - m_new);
      float p1 = __expf(acc_s[i][1] - m_new);
      float ps = p0 + p1;
#pragma unroll
      for (int s = 1; s < 16; s <<= 1) ps += __shfl_xor(ps, s);
      l_i[i] = l_i[i] * alpha + ps;
      m_i[i] = m_new;
      p_ij[i][0] = p0;
      p_ij[i][1] = p1;
#pragma unroll
      for (int j = 0; j < 4; ++j) acc_o[i][j] *= alpha;
    }

    __syncthreads();   // everyone done reading K from KP
    // Write P tile (64x32, stride 36) into KP region
#pragma unroll
    for (int i = 0; i < 4; ++i) {
      KP[(r0 + i) * 36 + c0 + 0] = p_ij[i][0];
      KP[(r0 + i) * 36 + c0 + 1] = p_ij[i][1];
    }
    __syncthreads();

    // O += P @ V
#pragma unroll 8
    for (int k = 0; k < 32; ++k) {
      float4 vv = *(const float4*)&Vs[k][oc0];
#pragma unroll
      for (int i = 0; i < 4; ++i) {
        float pv = KP[(r0 + i) * 36 + k];
        acc_o[i][0] = fmaf(pv, vv.x, acc_o[i][0]);
        acc_o[i][1] = fmaf(pv, vv.y, acc_o[i][1]);
        acc_o[i][2] = fmaf(pv, vv.z, acc_o[i][2]);
        acc_o[i][3] = fmaf(pv, vv.w, acc_o[i][3]);
      }
    }
  }

  // Epilogue: y[b, q, h*64 + c] = O / l
#pragma unroll
  for (int i = 0; i < 4; ++i) {
    float inv = 1.f / l_i[i];
    int q = qt0 + r0 + i;
    float4 o;
    o.x = acc_o[i][0] * inv;
    o.y = acc_o[i][1] * inv;
    o.z = acc_o[i][2] * inv;
    o.w = acc_o[i][3] * inv;
    *(float4*)&y[((size_t)b * LQ + q) * EQ + h * 64 + oc0] = o;
  }
}

// ---------------------------------------------------------------------------
extern "C" void kernel_launch(void* const* d_in, const int* in_sizes, int n_in,
                              void* d_out, int out_size, void* d_ws, size_t ws_size,
                              hipStream_t stream) {
  const float* xt = (const float*)d_in[0];
  const float* xs = (const float*)d_in[1];
  const float* Wt = (const float*)d_in[2];
  const float* bt = (const float*)d_in[3];
  const float* Ws = (const float*)d_in[4];
  const float* bs = (const float*)d_in[5];
  const float* Wc = (const float*)d_in[6];
  const float* bc = (const float*)d_in[7];
  const float* lam_ts = (const float*)d_in[8];
  const float* lam_st = (const float*)d_in[9];
  const float* lam_ss = (const float*)d_in[10];
  float* out = (float*)d_out;

  // Workspace layout (fp32):
  float* ws = (float*)d_ws;
  float* qcat = ws;                              // BH*L*128 = 16,777,216
  float* kcat = ws + 16777216;                   // BH*L*128
  float* vbuf = ws + 33554432;                   // BH*L*64  =  8,388,608
  float* ybuf = ws + 41943040;                   // B*L*E    =  4,194,304

  // 1) t-proj: xt @ Wt + bt  -> qt, kt, vt (head layout)
  gemm_proj<<<dim3(3072 / 128, M_ROWS / 128), 256, 0, stream>>>(
      xt, Wt, bt, qcat, kcat, vbuf, 3072, 0);
  // 2) s-proj: xs @ Ws + bs  -> qs, ks
  gemm_proj<<<dim3(2048 / 128, M_ROWS / 128), 256, 0, stream>>>(
      xs, Ws, bs, qcat, kcat, nullptr, 2048, 1);
  // 3) combine keys + scale q
  combine_kernel<<<(BH * LQ * 16) / 256, 256, 0, stream>>>(
      qcat, kcat, lam_ts, lam_st, lam_ss);
  // 4) flash attention
  flash_attn<<<dim3(LQ / 64, BH), 256, 0, stream>>>(qcat, kcat, vbuf, ybuf);
  // 5) c_proj: y @ Wc + bc -> out
  gemm_proj<<<dim3(1024 / 128, M_ROWS / 128), 256, 0, stream>>>(
      ybuf, Wc, bc, out, nullptr, nullptr, 1024, 2);
}

// Round 2
// 909.733 us; speedup vs baseline: 2.1519x; 2.1519x over previous
//
#include <hip/hip_runtime.h>
#include <math.h>

// Problem constants: B=2, L=2048, E=1024, H=16, D=64
#define BQ 2
#define LQ 2048
#define EQ 1024
#define M_ROWS (BQ*LQ)          // 4096
#define BH (BQ*16)              // 32

typedef _Float16 f16x8 __attribute__((ext_vector_type(8)));
typedef _Float16 f16x4 __attribute__((ext_vector_type(4)));
typedef float f32x4 __attribute__((ext_vector_type(4)));

// ---------------------------------------------------------------------------
// Tiled fp32 GEMM (unchanged from R1): C = A(4096xK=1024) @ W(KxN) + bias.
// mode 0: t-proj N=3072 -> qt->qcat[:,0:64], kt->kcat[:,0:64], vt->v
// mode 1: s-proj N=2048 -> qs->qcat[:,64:128], ks->kcat[:,64:128]
// mode 2: plain  N=1024 -> out0
// ---------------------------------------------------------------------------
__global__ __launch_bounds__(256) void gemm_proj(
    const float* __restrict__ A, const float* __restrict__ W,
    const float* __restrict__ bias,
    float* __restrict__ out0, float* __restrict__ out1, float* __restrict__ out2,
    int N, int mode) {

  __shared__ float As[16][132];
  __shared__ float Bs[16][132];

  const int tid = threadIdx.x;
  const int tx = tid & 15;
  const int ty = tid >> 4;
  const int m0 = blockIdx.y * 128;
  const int n0 = blockIdx.x * 128;

  float acc[8][8];
#pragma unroll
  for (int i = 0; i < 8; ++i)
#pragma unroll
    for (int j = 0; j < 8; ++j) acc[i][j] = 0.f;

  for (int kt = 0; kt < 1024; kt += 16) {
#pragma unroll
    for (int p = 0; p < 2; ++p) {
      int idx = tid + p * 256;
      int row = idx >> 2;
      int k4 = (idx & 3) * 4;
      float4 av = *(const float4*)&A[(size_t)(m0 + row) * 1024 + kt + k4];
      As[k4 + 0][row] = av.x;
      As[k4 + 1][row] = av.y;
      As[k4 + 2][row] = av.z;
      As[k4 + 3][row] = av.w;
    }
#pragma unroll
    for (int p = 0; p < 2; ++p) {
      int idx = tid + p * 256;
      int row = idx >> 5;
      int c4 = (idx & 31) * 4;
      *(float4*)&Bs[row][c4] = *(const float4*)&W[(size_t)(kt + row) * N + n0 + c4];
    }
    __syncthreads();

#pragma unroll
    for (int k = 0; k < 16; ++k) {
      float a[8], b[8];
      *(float4*)&a[0] = *(const float4*)&As[k][ty * 8];
      *(float4*)&a[4] = *(const float4*)&As[k][ty * 8 + 4];
      *(float4*)&b[0] = *(const float4*)&Bs[k][tx * 8];
      *(float4*)&b[4] = *(const float4*)&Bs[k][tx * 8 + 4];
#pragma unroll
      for (int i = 0; i < 8; ++i)
#pragma unroll
        for (int j = 0; j < 8; ++j)
          acc[i][j] = fmaf(a[i], b[j], acc[i][j]);
    }
    __syncthreads();
  }

  if (mode == 2) {
#pragma unroll
    for (int i = 0; i < 8; ++i) {
      int row = m0 + ty * 8 + i;
#pragma unroll
      for (int j = 0; j < 8; ++j) {
        int col = n0 + tx * 8 + j;
        out0[(size_t)row * N + col] = acc[i][j] + bias[col];
      }
    }
  } else {
#pragma unroll
    for (int i = 0; i < 8; ++i) {
      int row = m0 + ty * 8 + i;
      int bb = row >> 11;
      int ll = row & 2047;
#pragma unroll
      for (int j = 0; j < 8; ++j) {
        int col = n0 + tx * 8 + j;
        float val = acc[i][j] + bias[col];
        int which = col >> 10;
        int e = col & 1023;
        int hh = e >> 6;
        int dd = e & 63;
        size_t rowhd = (size_t)(bb * 16 + hh) * 2048 + ll;
        if (mode == 0) {
          if (which == 0)      out0[rowhd * 128 + dd] = val;
          else if (which == 1) out1[rowhd * 128 + dd] = val;
          else                 out2[rowhd * 64 + dd] = val;
        } else {
          if (which == 0)      out0[rowhd * 128 + 64 + dd] = val;
          else                 out1[rowhd * 128 + 64 + dd] = val;
        }
      }
    }
  }
}

// ---------------------------------------------------------------------------
// Combine keys: k1 = kt + lts*ks, k2 = lst*kt + lss*ks; scale q by 1/8.
// ---------------------------------------------------------------------------
__global__ __launch_bounds__(256) void combine_kernel(
    float* __restrict__ qcat, float* __restrict__ kcat,
    const float* __restrict__ lam_ts, const float* __restrict__ lam_st,
    const float* __restrict__ lam_ss) {
  int idx = blockIdx.x * 256 + threadIdx.x;
  int row = idx >> 4;
  int d4 = (idx & 15) * 4;
  float lts = lam_ts[0], lst = lam_st[0], lss = lam_ss[0];
  size_t base = (size_t)row * 128;

  float4 kt = *(float4*)&kcat[base + d4];
  float4 ks = *(float4*)&kcat[base + 64 + d4];
  float4 k1, k2;
  k1.x = kt.x + lts * ks.x;  k1.y = kt.y + lts * ks.y;
  k1.z = kt.z + lts * ks.z;  k1.w = kt.w + lts * ks.w;
  k2.x = lst * kt.x + lss * ks.x;  k2.y = lst * kt.y + lss * ks.y;
  k2.z = lst * kt.z + lss * ks.z;  k2.w = lst * kt.w + lss * ks.w;
  *(float4*)&kcat[base + d4] = k1;
  *(float4*)&kcat[base + 64 + d4] = k2;

  float4 q1 = *(float4*)&qcat[base + d4];
  float4 q2 = *(float4*)&qcat[base + 64 + d4];
  q1.x *= 0.125f; q1.y *= 0.125f; q1.z *= 0.125f; q1.w *= 0.125f;
  q2.x *= 0.125f; q2.y *= 0.125f; q2.z *= 0.125f; q2.w *= 0.125f;
  *(float4*)&qcat[base + d4] = q1;
  *(float4*)&qcat[base + 64 + d4] = q2;
}

// ---------------------------------------------------------------------------
// MFMA flash attention (fp16 inputs, fp32 accum).
// Block = 256 thr (4 waves), Q-tile = 128 rows (32/wave), K-tile = 64 keys.
// S computed transposed: S^T[key][qrow] = mfma(A=K-frag, B=Q-frag) so the
// P round-trip writes pack to ds_write_b64. Q-frags live in registers.
// MFMA 16x16x32_f16 layouts (m89/m120-verified, dtype-independent):
//   A/B: idx = lane&15 (m or n), k = (lane>>4)*8 + j
//   C/D: col = lane&15, row = (lane>>4)*4 + reg
// LDS: Ksh 64x136 f16 (17408) + Vt 64x72 f16 (9216) + Psh 4x32x72 f16 (18432)
//      = 45056 B -> 3 blocks/CU capacity (grid gives 2/CU).
// Strides 136/72 halfwords -> 2-way bank aliasing only (free, m136).
// ---------------------------------------------------------------------------
__global__ __launch_bounds__(256) void flash_attn_mfma(
    const float* __restrict__ qcat, const float* __restrict__ kcat,
    const float* __restrict__ v, float* __restrict__ y) {
  const int bh = blockIdx.y;                 // 0..31
  const int qt0 = blockIdx.x * 128;
  const int b = bh >> 4, h = bh & 15;
  const float* Qg = qcat + (size_t)bh * LQ * 128;
  const float* Kg = kcat + (size_t)bh * LQ * 128;
  const float* Vg = v + (size_t)bh * LQ * 64;

  __shared__ _Float16 Ksh[64 * 136];
  __shared__ _Float16 Vt[64 * 72];
  __shared__ _Float16 Psh[4 * 32 * 72];

  const int tid = threadIdx.x;
  const int w = tid >> 6;                    // wave 0..3
  const int lane = tid & 63;
  const int quad = lane >> 4;                // 0..3
  const int l15 = lane & 15;

  // --- Q fragments (resident): wave w owns q-rows qt0 + w*32 + [0,32) ---
  // B-layout: n = qb*16 + l15 (qrow), k = db*32 + quad*8 + j (dim)
  f16x8 qf[2][4];
#pragma unroll
  for (int qb = 0; qb < 2; ++qb) {
#pragma unroll
    for (int db = 0; db < 4; ++db) {
      const float* qp = Qg + (size_t)(qt0 + w * 32 + qb * 16 + l15) * 128 + db * 32 + quad * 8;
      float4 q0 = *(const float4*)qp;
      float4 q1 = *(const float4*)(qp + 4);
      f16x8 r;
      r[0] = (_Float16)q0.x; r[1] = (_Float16)q0.y;
      r[2] = (_Float16)q0.z; r[3] = (_Float16)q0.w;
      r[4] = (_Float16)q1.x; r[5] = (_Float16)q1.y;
      r[6] = (_Float16)q1.z; r[7] = (_Float16)q1.w;
      qf[qb][db] = r;
    }
  }

  float m_i[2] = {-INFINITY, -INFINITY};
  float l_i[2] = {0.f, 0.f};
  f32x4 O[2][4];
#pragma unroll
  for (int mb = 0; mb < 2; ++mb)
#pragma unroll
    for (int nb = 0; nb < 4; ++nb) O[mb][nb] = (f32x4){0.f, 0.f, 0.f, 0.f};

  _Float16* Pw = &Psh[w * 32 * 72];

  for (int t = 0; t < LQ; t += 64) {
    __syncthreads();   // previous iteration's Ksh/Vt readers are done

    // Stage K tile: 64 keys x 128 dims fp32 -> fp16, coalesced float4 reads
#pragma unroll
    for (int p = 0; p < 8; ++p) {
      int idx = p * 256 + tid;
      int row = idx >> 5;             // key 0..63
      int c4 = (idx & 31) * 4;        // dim chunk
      float4 kv = *(const float4*)&Kg[(size_t)(t + row) * 128 + c4];
      f16x4 h4;
      h4[0] = (_Float16)kv.x; h4[1] = (_Float16)kv.y;
      h4[2] = (_Float16)kv.z; h4[3] = (_Float16)kv.w;
      *(f16x4*)&Ksh[row * 136 + c4] = h4;
    }
    // Stage V transposed: Vt[dim][key], key = lane (conflict-free writes)
#pragma unroll
    for (int p = 0; p < 4; ++p) {
      int d4 = (p * 4 + w) * 4;       // wave-uniform dim chunk
      float4 vv = *(const float4*)&Vg[(size_t)(t + lane) * 64 + d4];
      Vt[(d4 + 0) * 72 + lane] = (_Float16)vv.x;
      Vt[(d4 + 1) * 72 + lane] = (_Float16)vv.y;
      Vt[(d4 + 2) * 72 + lane] = (_Float16)vv.z;
      Vt[(d4 + 3) * 72 + lane] = (_Float16)vv.w;
    }
    __syncthreads();

    // S^T[key][qrow]: blocks kb(4 key) x qb(2 qrow), contraction over 128 dims
    f32x4 S[4][2];
#pragma unroll
    for (int kb = 0; kb < 4; ++kb)
#pragma unroll
      for (int qb = 0; qb < 2; ++qb) S[kb][qb] = (f32x4){0.f, 0.f, 0.f, 0.f};

#pragma unroll
    for (int db = 0; db < 4; ++db) {
      f16x8 af[4];
#pragma unroll
      for (int kb = 0; kb < 4; ++kb)
        af[kb] = *(f16x8*)&Ksh[(kb * 16 + l15) * 136 + db * 32 + quad * 8];
#pragma unroll
      for (int kb = 0; kb < 4; ++kb)
#pragma unroll
        for (int qb = 0; qb < 2; ++qb)
          S[kb][qb] = __builtin_amdgcn_mfma_f32_16x16x32_f16(af[kb], qf[qb][db], S[kb][qb], 0, 0, 0);
    }

    // Online softmax. Lane holds, for qrow = qb*16+l15: keys kb*16+quad*4+r.
    float alpha[2];
#pragma unroll
    for (int qb = 0; qb < 2; ++qb) {
      float mx = -INFINITY;
#pragma unroll
      for (int kb = 0; kb < 4; ++kb)
#pragma unroll
        for (int r = 0; r < 4; ++r) mx = fmaxf(mx, S[kb][qb][r]);
      mx = fmaxf(mx, __shfl_xor(mx, 16));
      mx = fmaxf(mx, __shfl_xor(mx, 32));
      float m_new = fmaxf(m_i[qb], mx);
      alpha[qb] = __expf(m_i[qb] - m_new);
      float s = 0.f;
#pragma unroll
      for (int kb = 0; kb < 4; ++kb)
#pragma unroll
        for (int r = 0; r < 4; ++r) {
          float p = __expf(S[kb][qb][r] - m_new);
          S[kb][qb][r] = p;
          s += p;
        }
      s += __shfl_xor(s, 16);
      s += __shfl_xor(s, 32);
      l_i[qb] = l_i[qb] * alpha[qb] + s;
      m_i[qb] = m_new;
    }

    // P -> LDS (per-wave region, packed b64 writes): Psh[qrow][key]
#pragma unroll
    for (int qb = 0; qb < 2; ++qb)
#pragma unroll
      for (int kb = 0; kb < 4; ++kb) {
        f16x4 p4;
        p4[0] = (_Float16)S[kb][qb][0];
        p4[1] = (_Float16)S[kb][qb][1];
        p4[2] = (_Float16)S[kb][qb][2];
        p4[3] = (_Float16)S[kb][qb][3];
        *(f16x4*)&Pw[(qb * 16 + l15) * 72 + kb * 16 + quad * 4] = p4;
      }

    // Rescale O by alpha (broadcast: row quad*4+r+16*mb owned by lane quad*4+r)
#pragma unroll
    for (int mb = 0; mb < 2; ++mb)
#pragma unroll
      for (int r = 0; r < 4; ++r) {
        float ab = __shfl(alpha[mb], quad * 4 + r);
#pragma unroll
        for (int nb = 0; nb < 4; ++nb) O[mb][nb][r] *= ab;
      }

    // O += P @ V  (A = P rows, B = Vt rows; contraction over 64 keys)
#pragma unroll
    for (int kb2 = 0; kb2 < 2; ++kb2) {
      f16x8 ap[2], bv[4];
#pragma unroll
      for (int mb = 0; mb < 2; ++mb)
        ap[mb] = *(f16x8*)&Pw[(mb * 16 + l15) * 72 + kb2 * 32 + quad * 8];
#pragma unroll
      for (int nb = 0; nb < 4; ++nb)
        bv[nb] = *(f16x8*)&Vt[(nb * 16 + l15) * 72 + kb2 * 32 + quad * 8];
#pragma unroll
      for (int mb = 0; mb < 2; ++mb)
#pragma unroll
        for (int nb = 0; nb < 4; ++nb)
          O[mb][nb] = __builtin_amdgcn_mfma_f32_16x16x32_f16(ap[mb], bv[nb], O[mb][nb], 0, 0, 0);
    }
  }

  // Epilogue: y[b, qrow, h*64 + vdim] = O / l
#pragma unroll
  for (int mb = 0; mb < 2; ++mb)
#pragma unroll
    for (int r = 0; r < 4; ++r) {
      float li = __shfl(l_i[mb], quad * 4 + r);
      float inv = 1.f / li;
      int qrow = qt0 + w * 32 + mb * 16 + quad * 4 + r;
#pragma unroll
      for (int nb = 0; nb < 4; ++nb)
        y[((size_t)b * LQ + qrow) * EQ + h * 64 + nb * 16 + l15] = O[mb][nb][r] * inv;
    }
}

// ---------------------------------------------------------------------------
extern "C" void kernel_launch(void* const* d_in, const int* in_sizes, int n_in,
                              void* d_out, int out_size, void* d_ws, size_t ws_size,
                              hipStream_t stream) {
  const float* xt = (const float*)d_in[0];
  const float* xs = (const float*)d_in[1];
  const float* Wt = (const float*)d_in[2];
  const float* bt = (const float*)d_in[3];
  const float* Ws = (const float*)d_in[4];
  const float* bs = (const float*)d_in[5];
  const float* Wc = (const float*)d_in[6];
  const float* bc = (const float*)d_in[7];
  const float* lam_ts = (const float*)d_in[8];
  const float* lam_st = (const float*)d_in[9];
  const float* lam_ss = (const float*)d_in[10];
  float* out = (float*)d_out;

  float* ws = (float*)d_ws;
  float* qcat = ws;                              // BH*L*128
  float* kcat = ws + 16777216;                   // BH*L*128
  float* vbuf = ws + 33554432;                   // BH*L*64
  float* ybuf = ws + 41943040;                   // B*L*E

  gemm_proj<<<dim3(3072 / 128, M_ROWS / 128), 256, 0, stream>>>(
      xt, Wt, bt, qcat, kcat, vbuf, 3072, 0);
  gemm_proj<<<dim3(2048 / 128, M_ROWS / 128), 256, 0, stream>>>(
      xs, Ws, bs, qcat, kcat, nullptr, 2048, 1);
  combine_kernel<<<(BH * LQ * 16) / 256, 256, 0, stream>>>(
      qcat, kcat, lam_ts, lam_st, lam_ss);
  flash_attn_mfma<<<dim3(LQ / 128, BH), 256, 0, stream>>>(qcat, kcat, vbuf, ybuf);
  gemm_proj<<<dim3(1024 / 128, M_ROWS / 128), 256, 0, stream>>>(
      ybuf, Wc, bc, out, nullptr, nullptr, 1024, 2);
}

// Round 3
// 314.210 us; speedup vs baseline: 6.2305x; 2.8953x over previous
//
#include <hip/hip_runtime.h>
#include <math.h>

// Problem constants: B=2, L=2048, E=1024, H=16, D=64
#define LQ 2048
#define EQ 1024
#define M_ROWS 4096
#define BH 32

typedef _Float16 f16x8 __attribute__((ext_vector_type(8)));
typedef _Float16 f16x4 __attribute__((ext_vector_type(4)));
typedef float f32x4 __attribute__((ext_vector_type(4)));

__device__ __forceinline__ void async_ld16(const _Float16* g, _Float16* l) {
  __builtin_amdgcn_global_load_lds(
      (const __attribute__((address_space(1))) unsigned int*)g,
      (__attribute__((address_space(3))) unsigned int*)l, 16, 0, 0);
}

// ---------------------------------------------------------------------------
// Convert xt, xs (fp32) -> fp16, vectorized. 1M threads x 8 elements.
// ---------------------------------------------------------------------------
__global__ __launch_bounds__(256) void convert_x(
    const float* __restrict__ xt, const float* __restrict__ xs,
    _Float16* __restrict__ xt16, _Float16* __restrict__ xs16) {
  int i = blockIdx.x * 256 + threadIdx.x;          // 0..1048575
  const float* s; _Float16* d; size_t off;
  if (i < 524288) { s = xt; d = xt16; off = (size_t)i * 8; }
  else            { s = xs; d = xs16; off = (size_t)(i - 524288) * 8; }
  float4 a = *(const float4*)&s[off];
  float4 b = *(const float4*)&s[off + 4];
  f16x8 h;
  h[0] = (_Float16)a.x; h[1] = (_Float16)a.y; h[2] = (_Float16)a.z; h[3] = (_Float16)a.w;
  h[4] = (_Float16)b.x; h[5] = (_Float16)b.y; h[6] = (_Float16)b.z; h[7] = (_Float16)b.w;
  *(f16x8*)&d[off] = h;
}

// ---------------------------------------------------------------------------
// Transpose+convert weights: W[k][n] fp32 -> WT[n][k] fp16. All 3 weights in
// one launch, 32x32 LDS tiles. grid.x indexes 6144 total columns / 32.
// ---------------------------------------------------------------------------
__global__ __launch_bounds__(256) void transpose_w(
    const float* __restrict__ Wt, const float* __restrict__ Ws,
    const float* __restrict__ Wc,
    _Float16* __restrict__ WtT, _Float16* __restrict__ WsT,
    _Float16* __restrict__ WcT) {
  __shared__ float T[32][33];
  int tx = threadIdx.x & 31, ty = threadIdx.x >> 5;
  int c0 = blockIdx.x * 32;
  int k0 = blockIdx.y * 32;
  const float* W; _Float16* D; int Nw, cl;
  if (c0 < 3072)      { W = Wt; D = WtT; Nw = 3072; cl = c0; }
  else if (c0 < 5120) { W = Ws; D = WsT; Nw = 2048; cl = c0 - 3072; }
  else                { W = Wc; D = WcT; Nw = 1024; cl = c0 - 5120; }
#pragma unroll
  for (int j = 0; j < 4; ++j)
    T[ty + j * 8][tx] = W[(size_t)(k0 + ty + j * 8) * Nw + cl + tx];
  __syncthreads();
#pragma unroll
  for (int j = 0; j < 4; ++j)
    D[(size_t)(cl + ty + j * 8) * 1024 + k0 + tx] = (_Float16)T[tx][ty + j * 8];
}

// ---------------------------------------------------------------------------
// fp16 MFMA GEMM, m97 recipe: C[m][n] = sum_k A[m][k]*B[n][k] + bias[n].
// A: M x 1024 fp16 row-major. B: N x 1024 fp16 row-major (pre-transposed W).
// 128x128 tile, BK=32, 4 waves (2x2), each wave 4x4 tiles of 16x16x32_f16.
// Staging via global_load_lds width=16 with XOR chunk-swizzle so ds_read_b128
// fragment reads have only 2-way bank aliasing (free, m136).
// Epilogue modes: 0 t-proj scatter (q*,k*,v fp16; q scaled 1/8)
//                 1 s-proj scatter, 2 plain fp32 out.
// ---------------------------------------------------------------------------
__global__ __launch_bounds__(256) void gemm_bt(
    const _Float16* __restrict__ A, const _Float16* __restrict__ Bm,
    const float* __restrict__ bias,
    float* __restrict__ outf, _Float16* __restrict__ q16,
    _Float16* __restrict__ k16, _Float16* __restrict__ v16,
    int N, int mode) {
  __shared__ _Float16 Al[128 * 32];   // 8 KB, row-major [row][k], 64 B rows
  __shared__ _Float16 Bl[128 * 32];   // 8 KB

  const int tid = threadIdx.x;
  const int w = tid >> 6;
  const int lane = tid & 63;
  const int quad = lane >> 4;
  const int l15 = lane & 15;
  const int wm = w >> 1, wn = w & 1;
  const int m0 = blockIdx.y * 128;
  const int n0 = blockIdx.x * 128;

  // staging: lane -> (row within 16, swizzled 8-elem chunk)
  const int srow = lane >> 2;                                  // 0..15
  const int schunk = ((lane & 3) ^ ((lane >> 3) & 3)) * 8;     // fp16 offset

  f32x4 acc[4][4];
#pragma unroll
  for (int mb = 0; mb < 4; ++mb)
#pragma unroll
    for (int nb = 0; nb < 4; ++nb) acc[mb][nb] = (f32x4){0.f, 0.f, 0.f, 0.f};

  const int key = (l15 >> 1) & 3;     // frag-read swizzle key

  for (int kt = 0; kt < 1024; kt += 32) {
    __syncthreads();   // prior iteration's ds_reads complete
#pragma unroll
    for (int i = 0; i < 2; ++i) {
      int rt = w * 32 + i * 16;       // wave-uniform 16-row group base
      async_ld16(&A[(size_t)(m0 + rt + srow) * 1024 + kt + schunk], &Al[rt * 32]);
      async_ld16(&Bm[(size_t)(n0 + rt + srow) * 1024 + kt + schunk], &Bl[rt * 32]);
    }
    __syncthreads();   // drains vmcnt -> staged data visible

    f16x8 af[4], bf[4];
    const int pc = (quad ^ key) * 8;  // physical chunk for logical chunk quad
#pragma unroll
    for (int mb = 0; mb < 4; ++mb)
      af[mb] = *(f16x8*)&Al[(wm * 64 + mb * 16 + l15) * 32 + pc];
#pragma unroll
    for (int nb = 0; nb < 4; ++nb)
      bf[nb] = *(f16x8*)&Bl[(wn * 64 + nb * 16 + l15) * 32 + pc];
#pragma unroll
    for (int mb = 0; mb < 4; ++mb)
#pragma unroll
      for (int nb = 0; nb < 4; ++nb)
        acc[mb][nb] = __builtin_amdgcn_mfma_f32_16x16x32_f16(af[mb], bf[nb], acc[mb][nb], 0, 0, 0);
  }

  // Epilogue. C/D layout: row = quad*4+r (m), col = l15 (n).
#pragma unroll
  for (int mb = 0; mb < 4; ++mb)
#pragma unroll
    for (int nb = 0; nb < 4; ++nb)
#pragma unroll
      for (int r = 0; r < 4; ++r) {
        int row = m0 + wm * 64 + mb * 16 + quad * 4 + r;
        int col = n0 + wn * 64 + nb * 16 + l15;
        float val = acc[mb][nb][r] + bias[col];
        if (mode == 2) {
          outf[(size_t)row * 1024 + col] = val;
        } else {
          int bb = row >> 11, ll = row & 2047;
          int which = col >> 10, e = col & 1023;
          int hh = e >> 6, dd = e & 63;
          size_t rowhd = (size_t)(bb * 16 + hh) * 2048 + ll;
          if (mode == 0) {
            if (which == 0)      q16[rowhd * 128 + dd] = (_Float16)(val * 0.125f);
            else if (which == 1) k16[rowhd * 128 + dd] = (_Float16)val;
            else                 v16[rowhd * 64 + dd] = (_Float16)val;
          } else {
            if (which == 0) q16[rowhd * 128 + 64 + dd] = (_Float16)(val * 0.125f);
            else            k16[rowhd * 128 + 64 + dd] = (_Float16)val;
          }
        }
      }
}

// ---------------------------------------------------------------------------
// Combine keys in fp16: k1 = kt + lts*ks, k2 = lst*kt + lss*ks (fp32 math).
// ---------------------------------------------------------------------------
__global__ __launch_bounds__(256) void combine16(
    _Float16* __restrict__ kcat, const float* __restrict__ lam_ts,
    const float* __restrict__ lam_st, const float* __restrict__ lam_ss) {
  int idx = blockIdx.x * 256 + threadIdx.x;   // 0..524287
  int row = idx >> 3;
  int d8 = (idx & 7) * 8;
  float lts = lam_ts[0], lst = lam_st[0], lss = lam_ss[0];
  size_t base = (size_t)row * 128;
  f16x8 a = *(f16x8*)&kcat[base + d8];
  f16x8 b = *(f16x8*)&kcat[base + 64 + d8];
  f16x8 o1, o2;
#pragma unroll
  for (int e = 0; e < 8; ++e) {
    float kt = (float)a[e], ks = (float)b[e];
    o1[e] = (_Float16)(kt + lts * ks);
    o2[e] = (_Float16)(lst * kt + lss * ks);
  }
  *(f16x8*)&kcat[base + d8] = o1;
  *(f16x8*)&kcat[base + 64 + d8] = o2;
}

// ---------------------------------------------------------------------------
// MFMA flash attention (fp16 in, fp16 y out). Structure unchanged from R2
// (verified): 128 q-rows/block, 64-key tiles, S computed transposed,
// Q-frags register-resident, V transposed in LDS.
// ---------------------------------------------------------------------------
__global__ __launch_bounds__(256) void flash_attn_mfma(
    const _Float16* __restrict__ qcat, const _Float16* __restrict__ kcat,
    const _Float16* __restrict__ v, _Float16* __restrict__ y) {
  const int bh = blockIdx.y;
  const int qt0 = blockIdx.x * 128;
  const int b = bh >> 4, h = bh & 15;
  const _Float16* Qg = qcat + (size_t)bh * LQ * 128;
  const _Float16* Kg = kcat + (size_t)bh * LQ * 128;
  const _Float16* Vg = v + (size_t)bh * LQ * 64;

  __shared__ _Float16 Ksh[64 * 136];
  __shared__ _Float16 Vt[64 * 72];
  __shared__ _Float16 Psh[4 * 32 * 72];

  const int tid = threadIdx.x;
  const int w = tid >> 6;
  const int lane = tid & 63;
  const int quad = lane >> 4;
  const int l15 = lane & 15;

  // Q fragments resident: wave w owns q-rows qt0 + w*32 + [0,32)
  f16x8 qf[2][4];
#pragma unroll
  for (int qb = 0; qb < 2; ++qb)
#pragma unroll
    for (int db = 0; db < 4; ++db)
      qf[qb][db] = *(const f16x8*)&Qg[(size_t)(qt0 + w * 32 + qb * 16 + l15) * 128 + db * 32 + quad * 8];

  float m_i[2] = {-INFINITY, -INFINITY};
  float l_i[2] = {0.f, 0.f};
  f32x4 O[2][4];
#pragma unroll
  for (int mb = 0; mb < 2; ++mb)
#pragma unroll
    for (int nb = 0; nb < 4; ++nb) O[mb][nb] = (f32x4){0.f, 0.f, 0.f, 0.f};

  _Float16* Pw = &Psh[w * 32 * 72];

  for (int t = 0; t < LQ; t += 64) {
    __syncthreads();

    // K tile: 64 keys x 128 dims fp16, 16B chunks, padded stride 136
#pragma unroll
    for (int p = 0; p < 4; ++p) {
      int idx = p * 256 + tid;
      int row = idx >> 4;
      int c8 = (idx & 15) * 8;
      *(f16x8*)&Ksh[row * 136 + c8] = *(const f16x8*)&Kg[(size_t)(t + row) * 128 + c8];
    }
    // V transposed: Vt[dim][key]
#pragma unroll
    for (int p = 0; p < 2; ++p) {
      int d8 = (p * 4 + w) * 8;
      f16x8 vv = *(const f16x8*)&Vg[(size_t)(t + lane) * 64 + d8];
#pragma unroll
      for (int e = 0; e < 8; ++e) Vt[(d8 + e) * 72 + lane] = vv[e];
    }
    __syncthreads();

    // S^T[key][qrow]
    f32x4 S[4][2];
#pragma unroll
    for (int kb = 0; kb < 4; ++kb)
#pragma unroll
      for (int qb = 0; qb < 2; ++qb) S[kb][qb] = (f32x4){0.f, 0.f, 0.f, 0.f};

#pragma unroll
    for (int db = 0; db < 4; ++db) {
      f16x8 af[4];
#pragma unroll
      for (int kb = 0; kb < 4; ++kb)
        af[kb] = *(f16x8*)&Ksh[(kb * 16 + l15) * 136 + db * 32 + quad * 8];
#pragma unroll
      for (int kb = 0; kb < 4; ++kb)
#pragma unroll
        for (int qb = 0; qb < 2; ++qb)
          S[kb][qb] = __builtin_amdgcn_mfma_f32_16x16x32_f16(af[kb], qf[qb][db], S[kb][qb], 0, 0, 0);
    }

    // Online softmax
    float alpha[2];
#pragma unroll
    for (int qb = 0; qb < 2; ++qb) {
      float mx = -INFINITY;
#pragma unroll
      for (int kb = 0; kb < 4; ++kb)
#pragma unroll
        for (int r = 0; r < 4; ++r) mx = fmaxf(mx, S[kb][qb][r]);
      mx = fmaxf(mx, __shfl_xor(mx, 16));
      mx = fmaxf(mx, __shfl_xor(mx, 32));
      float m_new = fmaxf(m_i[qb], mx);
      alpha[qb] = __expf(m_i[qb] - m_new);
      float s = 0.f;
#pragma unroll
      for (int kb = 0; kb < 4; ++kb)
#pragma unroll
        for (int r = 0; r < 4; ++r) {
          float p = __expf(S[kb][qb][r] - m_new);
          S[kb][qb][r] = p;
          s += p;
        }
      s += __shfl_xor(s, 16);
      s += __shfl_xor(s, 32);
      l_i[qb] = l_i[qb] * alpha[qb] + s;
      m_i[qb] = m_new;
    }

    // P -> LDS (packed b64 writes)
#pragma unroll
    for (int qb = 0; qb < 2; ++qb)
#pragma unroll
      for (int kb = 0; kb < 4; ++kb) {
        f16x4 p4;
        p4[0] = (_Float16)S[kb][qb][0];
        p4[1] = (_Float16)S[kb][qb][1];
        p4[2] = (_Float16)S[kb][qb][2];
        p4[3] = (_Float16)S[kb][qb][3];
        *(f16x4*)&Pw[(qb * 16 + l15) * 72 + kb * 16 + quad * 4] = p4;
      }

    // Rescale O
#pragma unroll
    for (int mb = 0; mb < 2; ++mb)
#pragma unroll
      for (int r = 0; r < 4; ++r) {
        float ab = __shfl(alpha[mb], quad * 4 + r);
#pragma unroll
        for (int nb = 0; nb < 4; ++nb) O[mb][nb][r] *= ab;
      }

    // O += P @ V
#pragma unroll
    for (int kb2 = 0; kb2 < 2; ++kb2) {
      f16x8 ap[2], bv[4];
#pragma unroll
      for (int mb = 0; mb < 2; ++mb)
        ap[mb] = *(f16x8*)&Pw[(mb * 16 + l15) * 72 + kb2 * 32 + quad * 8];
#pragma unroll
      for (int nb = 0; nb < 4; ++nb)
        bv[nb] = *(f16x8*)&Vt[(nb * 16 + l15) * 72 + kb2 * 32 + quad * 8];
#pragma unroll
      for (int mb = 0; mb < 2; ++mb)
#pragma unroll
        for (int nb = 0; nb < 4; ++nb)
          O[mb][nb] = __builtin_amdgcn_mfma_f32_16x16x32_f16(ap[mb], bv[nb], O[mb][nb], 0, 0, 0);
    }
  }

  // Epilogue: y (fp16)
#pragma unroll
  for (int mb = 0; mb < 2; ++mb)
#pragma unroll
    for (int r = 0; r < 4; ++r) {
      float li = __shfl(l_i[mb], quad * 4 + r);
      float inv = 1.f / li;
      int qrow = qt0 + w * 32 + mb * 16 + quad * 4 + r;
#pragma unroll
      for (int nb = 0; nb < 4; ++nb)
        y[((size_t)b * LQ + qrow) * EQ + h * 64 + nb * 16 + l15] = (_Float16)(O[mb][nb][r] * inv);
    }
}

// ---------------------------------------------------------------------------
extern "C" void kernel_launch(void* const* d_in, const int* in_sizes, int n_in,
                              void* d_out, int out_size, void* d_ws, size_t ws_size,
                              hipStream_t stream) {
  const float* xt = (const float*)d_in[0];
  const float* xs = (const float*)d_in[1];
  const float* Wt = (const float*)d_in[2];
  const float* bt = (const float*)d_in[3];
  const float* Ws = (const float*)d_in[4];
  const float* bs = (const float*)d_in[5];
  const float* Wc = (const float*)d_in[6];
  const float* bc = (const float*)d_in[7];
  const float* lam_ts = (const float*)d_in[8];
  const float* lam_st = (const float*)d_in[9];
  const float* lam_ss = (const float*)d_in[10];
  float* out = (float*)d_out;

  _Float16* w16 = (_Float16*)d_ws;
  _Float16* xt16 = w16;                       // 4,194,304
  _Float16* xs16 = xt16 + 4194304;            // 4,194,304
  _Float16* WtT  = xs16 + 4194304;            // 3,145,728
  _Float16* WsT  = WtT + 3145728;             // 2,097,152
  _Float16* WcT  = WsT + 2097152;             // 1,048,576
  _Float16* qcat = WcT + 1048576;             // 8,388,608  [bh][l][128]
  _Float16* kcat = qcat + 8388608;            // 8,388,608
  _Float16* vbuf = kcat + 8388608;            // 4,194,304  [bh][l][64]
  _Float16* ybuf = vbuf + 4194304;            // 4,194,304  [b*l][1024]

  convert_x<<<4096, 256, 0, stream>>>(xt, xs, xt16, xs16);
  transpose_w<<<dim3(192, 32), 256, 0, stream>>>(Wt, Ws, Wc, WtT, WsT, WcT);
  gemm_bt<<<dim3(24, 32), 256, 0, stream>>>(
      xt16, WtT, bt, nullptr, qcat, kcat, vbuf, 3072, 0);
  gemm_bt<<<dim3(16, 32), 256, 0, stream>>>(
      xs16, WsT, bs, nullptr, qcat, kcat, nullptr, 2048, 1);
  combine16<<<2048, 256, 0, stream>>>(kcat, lam_ts, lam_st, lam_ss);
  flash_attn_mfma<<<dim3(16, 32), 256, 0, stream>>>(qcat, kcat, vbuf, ybuf);
  gemm_bt<<<dim3(8, 32), 256, 0, stream>>>(
      ybuf, WcT, bc, out, nullptr, nullptr, nullptr, 1024, 2);
}

// Round 4
// 304.667 us; speedup vs baseline: 6.4257x; 1.0313x over previous
//
#include <hip/hip_runtime.h>
#include <math.h>

// Problem constants: B=2, L=2048, E=1024, H=16, D=64
#define LQ 2048
#define EQ 1024
#define M_ROWS 4096
#define BH 32

typedef _Float16 f16x8 __attribute__((ext_vector_type(8)));
typedef _Float16 f16x4 __attribute__((ext_vector_type(4)));
typedef float f32x4 __attribute__((ext_vector_type(4)));

// q pre-scale: 1/sqrt(64) * log2(e)  -> softmax in exp2 domain
#define QSCALE 0.1803368801111204f

__device__ __forceinline__ void async_ld16(const _Float16* g, _Float16* l) {
  __builtin_amdgcn_global_load_lds(
      (const __attribute__((address_space(1))) unsigned int*)g,
      (__attribute__((address_space(3))) unsigned int*)l, 16, 0, 0);
}

// ---------------------------------------------------------------------------
// Convert xt, xs (fp32) -> fp16, vectorized. 1M threads x 8 elements.
// ---------------------------------------------------------------------------
__global__ __launch_bounds__(256) void convert_x(
    const float* __restrict__ xt, const float* __restrict__ xs,
    _Float16* __restrict__ xt16, _Float16* __restrict__ xs16) {
  int i = blockIdx.x * 256 + threadIdx.x;          // 0..1048575
  const float* s; _Float16* d; size_t off;
  if (i < 524288) { s = xt; d = xt16; off = (size_t)i * 8; }
  else            { s = xs; d = xs16; off = (size_t)(i - 524288) * 8; }
  float4 a = *(const float4*)&s[off];
  float4 b = *(const float4*)&s[off + 4];
  f16x8 h;
  h[0] = (_Float16)a.x; h[1] = (_Float16)a.y; h[2] = (_Float16)a.z; h[3] = (_Float16)a.w;
  h[4] = (_Float16)b.x; h[5] = (_Float16)b.y; h[6] = (_Float16)b.z; h[7] = (_Float16)b.w;
  *(f16x8*)&d[off] = h;
}

// ---------------------------------------------------------------------------
// Transpose+convert weights: W[k][n] fp32 -> WT[n][k] fp16.
// ---------------------------------------------------------------------------
__global__ __launch_bounds__(256) void transpose_w(
    const float* __restrict__ Wt, const float* __restrict__ Ws,
    const float* __restrict__ Wc,
    _Float16* __restrict__ WtT, _Float16* __restrict__ WsT,
    _Float16* __restrict__ WcT) {
  __shared__ float T[32][33];
  int tx = threadIdx.x & 31, ty = threadIdx.x >> 5;
  int c0 = blockIdx.x * 32;
  int k0 = blockIdx.y * 32;
  const float* W; _Float16* D; int Nw, cl;
  if (c0 < 3072)      { W = Wt; D = WtT; Nw = 3072; cl = c0; }
  else if (c0 < 5120) { W = Ws; D = WsT; Nw = 2048; cl = c0 - 3072; }
  else                { W = Wc; D = WcT; Nw = 1024; cl = c0 - 5120; }
#pragma unroll
  for (int j = 0; j < 4; ++j)
    T[ty + j * 8][tx] = W[(size_t)(k0 + ty + j * 8) * Nw + cl + tx];
  __syncthreads();
#pragma unroll
  for (int j = 0; j < 4; ++j)
    D[(size_t)(cl + ty + j * 8) * 1024 + k0 + tx] = (_Float16)T[tx][ty + j * 8];
}

// ---------------------------------------------------------------------------
// fp16 MFMA GEMM (m97 recipe, unchanged from R3 except QSCALE).
// ---------------------------------------------------------------------------
__global__ __launch_bounds__(256) void gemm_bt(
    const _Float16* __restrict__ A, const _Float16* __restrict__ Bm,
    const float* __restrict__ bias,
    float* __restrict__ outf, _Float16* __restrict__ q16,
    _Float16* __restrict__ k16, _Float16* __restrict__ v16,
    int N, int mode) {
  __shared__ _Float16 Al[128 * 32];
  __shared__ _Float16 Bl[128 * 32];

  const int tid = threadIdx.x;
  const int w = tid >> 6;
  const int lane = tid & 63;
  const int quad = lane >> 4;
  const int l15 = lane & 15;
  const int wm = w >> 1, wn = w & 1;
  const int m0 = blockIdx.y * 128;
  const int n0 = blockIdx.x * 128;

  const int srow = lane >> 2;
  const int schunk = ((lane & 3) ^ ((lane >> 3) & 3)) * 8;

  f32x4 acc[4][4];
#pragma unroll
  for (int mb = 0; mb < 4; ++mb)
#pragma unroll
    for (int nb = 0; nb < 4; ++nb) acc[mb][nb] = (f32x4){0.f, 0.f, 0.f, 0.f};

  const int key = (l15 >> 1) & 3;

  for (int kt = 0; kt < 1024; kt += 32) {
    __syncthreads();
#pragma unroll
    for (int i = 0; i < 2; ++i) {
      int rt = w * 32 + i * 16;
      async_ld16(&A[(size_t)(m0 + rt + srow) * 1024 + kt + schunk], &Al[rt * 32]);
      async_ld16(&Bm[(size_t)(n0 + rt + srow) * 1024 + kt + schunk], &Bl[rt * 32]);
    }
    __syncthreads();

    f16x8 af[4], bf[4];
    const int pc = (quad ^ key) * 8;
#pragma unroll
    for (int mb = 0; mb < 4; ++mb)
      af[mb] = *(f16x8*)&Al[(wm * 64 + mb * 16 + l15) * 32 + pc];
#pragma unroll
    for (int nb = 0; nb < 4; ++nb)
      bf[nb] = *(f16x8*)&Bl[(wn * 64 + nb * 16 + l15) * 32 + pc];
#pragma unroll
    for (int mb = 0; mb < 4; ++mb)
#pragma unroll
      for (int nb = 0; nb < 4; ++nb)
        acc[mb][nb] = __builtin_amdgcn_mfma_f32_16x16x32_f16(af[mb], bf[nb], acc[mb][nb], 0, 0, 0);
  }

#pragma unroll
  for (int mb = 0; mb < 4; ++mb)
#pragma unroll
    for (int nb = 0; nb < 4; ++nb)
#pragma unroll
      for (int r = 0; r < 4; ++r) {
        int row = m0 + wm * 64 + mb * 16 + quad * 4 + r;
        int col = n0 + wn * 64 + nb * 16 + l15;
        float val = acc[mb][nb][r] + bias[col];
        if (mode == 2) {
          outf[(size_t)row * 1024 + col] = val;
        } else {
          int bb = row >> 11, ll = row & 2047;
          int which = col >> 10, e = col & 1023;
          int hh = e >> 6, dd = e & 63;
          size_t rowhd = (size_t)(bb * 16 + hh) * 2048 + ll;
          if (mode == 0) {
            if (which == 0)      q16[rowhd * 128 + dd] = (_Float16)(val * QSCALE);
            else if (which == 1) k16[rowhd * 128 + dd] = (_Float16)val;
            else                 v16[rowhd * 64 + dd] = (_Float16)val;
          } else {
            if (which == 0) q16[rowhd * 128 + 64 + dd] = (_Float16)(val * QSCALE);
            else            k16[rowhd * 128 + 64 + dd] = (_Float16)val;
          }
        }
      }
}

// ---------------------------------------------------------------------------
// Combine keys in fp16: k1 = kt + lts*ks, k2 = lst*kt + lss*ks (fp32 math).
// ---------------------------------------------------------------------------
__global__ __launch_bounds__(256) void combine16(
    _Float16* __restrict__ kcat, const float* __restrict__ lam_ts,
    const float* __restrict__ lam_st, const float* __restrict__ lam_ss) {
  int idx = blockIdx.x * 256 + threadIdx.x;
  int row = idx >> 3;
  int d8 = (idx & 7) * 8;
  float lts = lam_ts[0], lst = lam_st[0], lss = lam_ss[0];
  size_t base = (size_t)row * 128;
  f16x8 a = *(f16x8*)&kcat[base + d8];
  f16x8 b = *(f16x8*)&kcat[base + 64 + d8];
  f16x8 o1, o2;
#pragma unroll
  for (int e = 0; e < 8; ++e) {
    float kt = (float)a[e], ks = (float)b[e];
    o1[e] = (_Float16)(kt + lts * ks);
    o2[e] = (_Float16)(lst * kt + lss * ks);
  }
  *(f16x8*)&kcat[base + d8] = o1;
  *(f16x8*)&kcat[base + 64 + d8] = o2;
}

// ---------------------------------------------------------------------------
// MFMA flash attention v2: 512 threads (8 waves), Q-tile 128 (16 rows/wave),
// K-tile 64, exp2-domain softmax (q pre-scaled by log2e/8).
// K staged via global_load_lds with XOR chunk swizzle (stride 128, no pad):
//   LDS[row][c] = Kglobal[row][c ^ (row&7)]; frag read uses pc = lc^(l15&7).
// V prefetched to registers one tile ahead, transposed into LDS.
// LDS: Ksh 64x128x2 = 16384, Vt 64x72x2 = 9216, Psh 8x16x72x2 = 18432
//      -> 44032 B; grid 512 blocks -> 2 blocks/CU, 16 waves/CU.
// ---------------------------------------------------------------------------
__global__ __launch_bounds__(512, 4) void flash_attn_mfma(
    const _Float16* __restrict__ qcat, const _Float16* __restrict__ kcat,
    const _Float16* __restrict__ v, _Float16* __restrict__ y) {
  const int bh = blockIdx.y;
  const int qt0 = blockIdx.x * 128;
  const int b = bh >> 4, h = bh & 15;
  const _Float16* Qg = qcat + (size_t)bh * LQ * 128;
  const _Float16* Kg = kcat + (size_t)bh * LQ * 128;
  const _Float16* Vg = v + (size_t)bh * LQ * 64;

  __shared__ _Float16 Ksh[64 * 128];
  __shared__ _Float16 Vt[64 * 72];
  __shared__ _Float16 Psh[8 * 16 * 72];

  const int tid = threadIdx.x;
  const int w = tid >> 6;                    // wave 0..7
  const int lane = tid & 63;
  const int quad = lane >> 4;
  const int l15 = lane & 15;

  // Q fragments resident: wave w owns q-rows qt0 + w*16 + [0,16)
  f16x8 qf[4];
#pragma unroll
  for (int db = 0; db < 4; ++db)
    qf[db] = *(const f16x8*)&Qg[(size_t)(qt0 + w * 16 + l15) * 128 + db * 32 + quad * 8];

  float m_i = -INFINITY;
  float l_i = 0.f;
  f32x4 O[4];
#pragma unroll
  for (int nb = 0; nb < 4; ++nb) O[nb] = (f32x4){0.f, 0.f, 0.f, 0.f};

  _Float16* Pw = &Psh[w * 16 * 72];

  // Async K staging: per a in {0,1}: rows w*8 + a*4 + (lane>>4), chunk lane&15,
  // source chunk XOR-swizzled by row&7. Per-lane source offsets are loop-invariant.
  int krow[2], kgc[2];
#pragma unroll
  for (int a = 0; a < 2; ++a) {
    krow[a] = w * 8 + a * 4 + (lane >> 4);
    kgc[a] = (lane & 15) ^ (krow[a] & 7);
  }
  // V prefetch: wave w covers dims w*8..w*8+7 of key (t + lane)
  const _Float16* vsrc = Vg + (size_t)lane * 64 + w * 8;
  f16x8 vv = *(const f16x8*)vsrc;

  for (int t = 0; t < LQ; t += 64) {
    __syncthreads();   // prior iteration's Ksh/Vt readers are done

    // Fire async K DMA (16B/lane, swizzled source)
#pragma unroll
    for (int a = 0; a < 2; ++a)
      async_ld16(&Kg[(size_t)(t + krow[a]) * 128 + kgc[a] * 8],
                 &Ksh[(w * 8 + a * 4) * 128]);

    // Write prefetched V (transposed): Vt[dim][key]
#pragma unroll
    for (int e = 0; e < 8; ++e) Vt[(w * 8 + e) * 72 + lane] = vv[e];
    // Prefetch next V tile
    if (t + 64 < LQ) vv = *(const f16x8*)(vsrc + (size_t)(t + 64) * 64);

    __syncthreads();   // drains async K (vmcnt) + V writes

    // S^T[key][qrow=l15]: contraction over 128 dims, swizzled Ksh reads
    f32x4 S[4];
#pragma unroll
    for (int kb = 0; kb < 4; ++kb) S[kb] = (f32x4){0.f, 0.f, 0.f, 0.f};
#pragma unroll
    for (int db = 0; db < 4; ++db) {
      const int pc = ((db * 4 + quad) ^ (l15 & 7)) * 8;
      f16x8 af[4];
#pragma unroll
      for (int kb = 0; kb < 4; ++kb)
        af[kb] = *(f16x8*)&Ksh[(kb * 16 + l15) * 128 + pc];
#pragma unroll
      for (int kb = 0; kb < 4; ++kb)
        S[kb] = __builtin_amdgcn_mfma_f32_16x16x32_f16(af[kb], qf[db], S[kb], 0, 0, 0);
    }

    // Online softmax in exp2 domain (scores already scaled by log2e/8)
    float mx = -INFINITY;
#pragma unroll
    for (int kb = 0; kb < 4; ++kb)
#pragma unroll
      for (int r = 0; r < 4; ++r) mx = fmaxf(mx, S[kb][r]);
    mx = fmaxf(mx, __shfl_xor(mx, 16));
    mx = fmaxf(mx, __shfl_xor(mx, 32));
    float m_new = fmaxf(m_i, mx);
    float alpha = __builtin_amdgcn_exp2f(m_i - m_new);
    float s = 0.f;
#pragma unroll
    for (int kb = 0; kb < 4; ++kb)
#pragma unroll
      for (int r = 0; r < 4; ++r) {
        float p = __builtin_amdgcn_exp2f(S[kb][r] - m_new);
        S[kb][r] = p;
        s += p;
      }
    s += __shfl_xor(s, 16);
    s += __shfl_xor(s, 32);
    l_i = l_i * alpha + s;
    m_i = m_new;

    // P -> LDS (per-wave region; same-wave RAW, no barrier needed)
#pragma unroll
    for (int kb = 0; kb < 4; ++kb) {
      f16x4 p4;
      p4[0] = (_Float16)S[kb][0];
      p4[1] = (_Float16)S[kb][1];
      p4[2] = (_Float16)S[kb][2];
      p4[3] = (_Float16)S[kb][3];
      *(f16x4*)&Pw[l15 * 72 + kb * 16 + quad * 4] = p4;
    }

    // Rescale O (alpha for qrow quad*4+r lives at lane quad*4+r)
#pragma unroll
    for (int r = 0; r < 4; ++r) {
      float ab = __shfl(alpha, quad * 4 + r);
#pragma unroll
      for (int nb = 0; nb < 4; ++nb) O[nb][r] *= ab;
    }

    // O += P @ V
#pragma unroll
    for (int kb2 = 0; kb2 < 2; ++kb2) {
      f16x8 ap = *(f16x8*)&Pw[l15 * 72 + kb2 * 32 + quad * 8];
      f16x8 bv[4];
#pragma unroll
      for (int nb = 0; nb < 4; ++nb)
        bv[nb] = *(f16x8*)&Vt[(nb * 16 + l15) * 72 + kb2 * 32 + quad * 8];
#pragma unroll
      for (int nb = 0; nb < 4; ++nb)
        O[nb] = __builtin_amdgcn_mfma_f32_16x16x32_f16(ap, bv[nb], O[nb], 0, 0, 0);
    }
  }

  // Epilogue: y fp16. O row = qrow quad*4+r, col = vdim nb*16+l15.
#pragma unroll
  for (int r = 0; r < 4; ++r) {
    float li = __shfl(l_i, quad * 4 + r);
    float inv = 1.f / li;
    int qrow = qt0 + w * 16 + quad * 4 + r;
#pragma unroll
    for (int nb = 0; nb < 4; ++nb)
      y[((size_t)b * LQ + qrow) * EQ + h * 64 + nb * 16 + l15] = (_Float16)(O[nb][r] * inv);
  }
}

// ---------------------------------------------------------------------------
extern "C" void kernel_launch(void* const* d_in, const int* in_sizes, int n_in,
                              void* d_out, int out_size, void* d_ws, size_t ws_size,
                              hipStream_t stream) {
  const float* xt = (const float*)d_in[0];
  const float* xs = (const float*)d_in[1];
  const float* Wt = (const float*)d_in[2];
  const float* bt = (const float*)d_in[3];
  const float* Ws = (const float*)d_in[4];
  const float* bs = (const float*)d_in[5];
  const float* Wc = (const float*)d_in[6];
  const float* bc = (const float*)d_in[7];
  const float* lam_ts = (const float*)d_in[8];
  const float* lam_st = (const float*)d_in[9];
  const float* lam_ss = (const float*)d_in[10];
  float* out = (float*)d_out;

  _Float16* w16 = (_Float16*)d_ws;
  _Float16* xt16 = w16;                       // 4,194,304
  _Float16* xs16 = xt16 + 4194304;            // 4,194,304
  _Float16* WtT  = xs16 + 4194304;            // 3,145,728
  _Float16* WsT  = WtT + 3145728;             // 2,097,152
  _Float16* WcT  = WsT + 2097152;             // 1,048,576
  _Float16* qcat = WcT + 1048576;             // 8,388,608  [bh][l][128]
  _Float16* kcat = qcat + 8388608;            // 8,388,608
  _Float16* vbuf = kcat + 8388608;            // 4,194,304  [bh][l][64]
  _Float16* ybuf = vbuf + 4194304;            // 4,194,304  [b*l][1024]

  convert_x<<<4096, 256, 0, stream>>>(xt, xs, xt16, xs16);
  transpose_w<<<dim3(192, 32), 256, 0, stream>>>(Wt, Ws, Wc, WtT, WsT, WcT);
  gemm_bt<<<dim3(24, 32), 256, 0, stream>>>(
      xt16, WtT, bt, nullptr, qcat, kcat, vbuf, 3072, 0);
  gemm_bt<<<dim3(16, 32), 256, 0, stream>>>(
      xs16, WsT, bs, nullptr, qcat, kcat, nullptr, 2048, 1);
  combine16<<<2048, 256, 0, stream>>>(kcat, lam_ts, lam_st, lam_ss);
  flash_attn_mfma<<<dim3(16, 32), 512, 0, stream>>>(qcat, kcat, vbuf, ybuf);
  gemm_bt<<<dim3(8, 32), 256, 0, stream>>>(
      ybuf, WcT, bc, out, nullptr, nullptr, nullptr, 1024, 2);
}

// Round 5
// 292.702 us; speedup vs baseline: 6.6883x; 1.0409x over previous
//
#include <hip/hip_runtime.h>
#include <math.h>

// Problem constants: B=2, L=2048, E=1024, H=16, D=64
#define LQ 2048
#define EQ 1024
#define M_ROWS 4096
#define BH 32

typedef _Float16 f16x8 __attribute__((ext_vector_type(8)));
typedef _Float16 f16x4 __attribute__((ext_vector_type(4)));
typedef float f32x4 __attribute__((ext_vector_type(4)));
typedef float f32x16 __attribute__((ext_vector_type(16)));

// q pre-scale: 1/sqrt(64) * log2(e)  -> softmax in exp2 domain
#define QSCALE 0.1803368801111204f

__device__ __forceinline__ void async_ld16(const _Float16* g, _Float16* l) {
  __builtin_amdgcn_global_load_lds(
      (const __attribute__((address_space(1))) unsigned int*)g,
      (__attribute__((address_space(3))) unsigned int*)l, 16, 0, 0);
}

// ---------------------------------------------------------------------------
// Convert xt, xs (fp32) -> fp16.
// ---------------------------------------------------------------------------
__global__ __launch_bounds__(256) void convert_x(
    const float* __restrict__ xt, const float* __restrict__ xs,
    _Float16* __restrict__ xt16, _Float16* __restrict__ xs16) {
  int i = blockIdx.x * 256 + threadIdx.x;
  const float* s; _Float16* d; size_t off;
  if (i < 524288) { s = xt; d = xt16; off = (size_t)i * 8; }
  else            { s = xs; d = xs16; off = (size_t)(i - 524288) * 8; }
  float4 a = *(const float4*)&s[off];
  float4 b = *(const float4*)&s[off + 4];
  f16x8 h;
  h[0] = (_Float16)a.x; h[1] = (_Float16)a.y; h[2] = (_Float16)a.z; h[3] = (_Float16)a.w;
  h[4] = (_Float16)b.x; h[5] = (_Float16)b.y; h[6] = (_Float16)b.z; h[7] = (_Float16)b.w;
  *(f16x8*)&d[off] = h;
}

// ---------------------------------------------------------------------------
// Transpose+convert weights: W[k][n] fp32 -> WT[n][k] fp16.
// ---------------------------------------------------------------------------
__global__ __launch_bounds__(256) void transpose_w(
    const float* __restrict__ Wt, const float* __restrict__ Ws,
    const float* __restrict__ Wc,
    _Float16* __restrict__ WtT, _Float16* __restrict__ WsT,
    _Float16* __restrict__ WcT) {
  __shared__ float T[32][33];
  int tx = threadIdx.x & 31, ty = threadIdx.x >> 5;
  int c0 = blockIdx.x * 32;
  int k0 = blockIdx.y * 32;
  const float* W; _Float16* D; int Nw, cl;
  if (c0 < 3072)      { W = Wt; D = WtT; Nw = 3072; cl = c0; }
  else if (c0 < 5120) { W = Ws; D = WsT; Nw = 2048; cl = c0 - 3072; }
  else                { W = Wc; D = WcT; Nw = 1024; cl = c0 - 5120; }
#pragma unroll
  for (int j = 0; j < 4; ++j)
    T[ty + j * 8][tx] = W[(size_t)(k0 + ty + j * 8) * Nw + cl + tx];
  __syncthreads();
#pragma unroll
  for (int j = 0; j < 4; ++j)
    D[(size_t)(cl + ty + j * 8) * 1024 + k0 + tx] = (_Float16)T[tx][ty + j * 8];
}

// ---------------------------------------------------------------------------
// fp16 MFMA GEMM (m97 recipe). Epilogue modes:
//  0: t-proj scatter. q scaled by QSCALE -> qcat[:,0:64]; kt -> kcat[:,0:64];
//     v -> vT TRANSPOSED [bh][dim][key] (for flash V DMA staging).
//  1: s-proj scatter + FUSED key combine: reads kt (mode-0 output), writes
//     k1 = kt + lts*ks into kcat[:,0:64], k2 = lst*kt + lss*ks into [:,64:128].
//  2: plain fp32 out.
// ---------------------------------------------------------------------------
__global__ __launch_bounds__(256) void gemm_bt(
    const _Float16* __restrict__ A, const _Float16* __restrict__ Bm,
    const float* __restrict__ bias,
    float* __restrict__ outf, _Float16* __restrict__ q16,
    _Float16* __restrict__ k16, _Float16* __restrict__ v16,
    const float* __restrict__ lam_ts, const float* __restrict__ lam_st,
    const float* __restrict__ lam_ss,
    int N, int mode) {
  __shared__ _Float16 Al[128 * 32];
  __shared__ _Float16 Bl[128 * 32];

  const int tid = threadIdx.x;
  const int w = tid >> 6;
  const int lane = tid & 63;
  const int quad = lane >> 4;
  const int l15 = lane & 15;
  const int wm = w >> 1, wn = w & 1;
  const int m0 = blockIdx.y * 128;
  const int n0 = blockIdx.x * 128;

  const int srow = lane >> 2;
  const int schunk = ((lane & 3) ^ ((lane >> 3) & 3)) * 8;

  float lts = 0.f, lst = 0.f, lss = 0.f;
  if (mode == 1) { lts = lam_ts[0]; lst = lam_st[0]; lss = lam_ss[0]; }

  f32x4 acc[4][4];
#pragma unroll
  for (int mb = 0; mb < 4; ++mb)
#pragma unroll
    for (int nb = 0; nb < 4; ++nb) acc[mb][nb] = (f32x4){0.f, 0.f, 0.f, 0.f};

  const int key = (l15 >> 1) & 3;

  for (int kt = 0; kt < 1024; kt += 32) {
    __syncthreads();
#pragma unroll
    for (int i = 0; i < 2; ++i) {
      int rt = w * 32 + i * 16;
      async_ld16(&A[(size_t)(m0 + rt + srow) * 1024 + kt + schunk], &Al[rt * 32]);
      async_ld16(&Bm[(size_t)(n0 + rt + srow) * 1024 + kt + schunk], &Bl[rt * 32]);
    }
    __syncthreads();

    f16x8 af[4], bf[4];
    const int pc = (quad ^ key) * 8;
#pragma unroll
    for (int mb = 0; mb < 4; ++mb)
      af[mb] = *(f16x8*)&Al[(wm * 64 + mb * 16 + l15) * 32 + pc];
#pragma unroll
    for (int nb = 0; nb < 4; ++nb)
      bf[nb] = *(f16x8*)&Bl[(wn * 64 + nb * 16 + l15) * 32 + pc];
#pragma unroll
    for (int mb = 0; mb < 4; ++mb)
#pragma unroll
      for (int nb = 0; nb < 4; ++nb)
        acc[mb][nb] = __builtin_amdgcn_mfma_f32_16x16x32_f16(af[mb], bf[nb], acc[mb][nb], 0, 0, 0);
  }

#pragma unroll
  for (int mb = 0; mb < 4; ++mb)
#pragma unroll
    for (int nb = 0; nb < 4; ++nb)
#pragma unroll
      for (int r = 0; r < 4; ++r) {
        int row = m0 + wm * 64 + mb * 16 + quad * 4 + r;
        int col = n0 + wn * 64 + nb * 16 + l15;
        float val = acc[mb][nb][r] + bias[col];
        if (mode == 2) {
          outf[(size_t)row * 1024 + col] = val;
        } else {
          int bb = row >> 11, ll = row & 2047;
          int which = col >> 10, e = col & 1023;
          int hh = e >> 6, dd = e & 63;
          size_t rowhd = (size_t)(bb * 16 + hh) * 2048 + ll;
          if (mode == 0) {
            if (which == 0)      q16[rowhd * 128 + dd] = (_Float16)(val * QSCALE);
            else if (which == 1) k16[rowhd * 128 + dd] = (_Float16)val;
            else                 v16[((size_t)(bb * 16 + hh) * 64 + dd) * 2048 + ll] = (_Float16)val;
          } else {
            if (which == 0) {
              q16[rowhd * 128 + 64 + dd] = (_Float16)(val * QSCALE);
            } else {
              float ktv = (float)k16[rowhd * 128 + dd];   // written by mode 0
              float ksv = val;
              k16[rowhd * 128 + dd]      = (_Float16)(ktv + lts * ksv);
              k16[rowhd * 128 + 64 + dd] = (_Float16)(lst * ktv + lss * ksv);
            }
          }
        }
      }
}

// ---------------------------------------------------------------------------
// MFMA flash attention v3: 32x32x16 MFMA, O^T formulation.
// Block = 256 thr (4 waves), each wave owns 32 q-rows (Q-tile 128), K-tile 64.
// S^T = mfma(A=K-frag, B=Q-frag)  -> C/D col = qrow = lane&31.
// O^T = mfma(A=V^T-frag, B=P^T)   -> C/D col = qrow = lane&31.
//   => softmax m/l/alpha are LANE-LOCAL; zero broadcast shuffles.
// 32x32x16_f16 layouts: A[m=lane&31][k=(lane>>5)*8+j], B[k][n=lane&31],
//   C/D col=lane&31, row=(reg&3)+8*(reg>>2)+4*(lane>>5) (m74/m101-verified).
// K and V both staged via global_load_lds w=16 with XOR chunk swizzle
// (chunk_phys = chunk_log ^ (row&7)); V pre-transposed [bh][dim][key] in HBM.
// LDS: Ksh 64x128x2=16384 + Vsh 64x64x2=8192 + Psh 4x32x72x2=18432 = 43008 B.
// ---------------------------------------------------------------------------
__global__ __launch_bounds__(256, 2) void flash_attn_mfma(
    const _Float16* __restrict__ qcat, const _Float16* __restrict__ kcat,
    const _Float16* __restrict__ vT, _Float16* __restrict__ y) {
  const int bh = blockIdx.y;
  const int qt0 = blockIdx.x * 128;
  const int b = bh >> 4, h = bh & 15;
  const _Float16* Qg = qcat + (size_t)bh * LQ * 128;
  const _Float16* Kg = kcat + (size_t)bh * LQ * 128;
  const _Float16* Vg = vT + (size_t)bh * 64 * LQ;     // [dim][key]

  __shared__ _Float16 Ksh[64 * 128];
  __shared__ _Float16 Vsh[64 * 64];
  __shared__ _Float16 Psh[4 * 32 * 72];

  const int tid = threadIdx.x;
  const int w = tid >> 6;                    // wave 0..3
  const int lane = tid & 63;
  const int half = lane >> 5;                // 0/1
  const int l31 = lane & 31;

  // Q B-frags resident: wave w owns qrows qt0 + w*32 + [0,32)
  f16x8 qf[8];
#pragma unroll
  for (int db = 0; db < 8; ++db)
    qf[db] = *(const f16x8*)&Qg[(size_t)(qt0 + w * 32 + l31) * 128 + db * 16 + half * 8];

  float m_i = -INFINITY;
  float l_i = 0.f;
  f32x16 O[2];
#pragma unroll
  for (int nt = 0; nt < 2; ++nt)
#pragma unroll
    for (int r = 0; r < 16; ++r) O[nt][r] = 0.f;

  _Float16* Pw = &Psh[w * 32 * 72];

  for (int t = 0; t < LQ; t += 64) {
    __syncthreads();   // prior iteration's Ksh/Vsh readers done

    // K DMA: 64 rows x 128 dims; 4 instr/wave, source chunk-swizzled
#pragma unroll
    for (int a = 0; a < 4; ++a) {
      int row = w * 16 + a * 4 + (lane >> 4);
      int sc = (lane & 15) ^ (row & 7);
      async_ld16(&Kg[(size_t)(t + row) * 128 + sc * 8], &Ksh[(w * 16 + a * 4) * 128]);
    }
    // V DMA: 64 dims x 64 keys; 2 instr/wave
#pragma unroll
    for (int a = 0; a < 2; ++a) {
      int row = w * 16 + a * 8 + (lane >> 3);          // dim
      int sc = (lane & 7) ^ (row & 7);
      async_ld16(&Vg[(size_t)row * LQ + t + sc * 8], &Vsh[(w * 16 + a * 8) * 64]);
    }
    __syncthreads();   // vmcnt drain -> staged data visible

    // S^T[key][qrow]: 2 key-tiles of 32, contraction over 128 dims (8 x k=16)
    f32x16 S[2];
#pragma unroll
    for (int kb = 0; kb < 2; ++kb)
#pragma unroll
      for (int r = 0; r < 16; ++r) S[kb][r] = 0.f;
#pragma unroll
    for (int db = 0; db < 8; ++db) {
      const int pc = ((db * 2 + half) ^ (lane & 7)) * 8;
      f16x8 af[2];
#pragma unroll
      for (int kb = 0; kb < 2; ++kb)
        af[kb] = *(f16x8*)&Ksh[(kb * 32 + l31) * 128 + pc];
#pragma unroll
      for (int kb = 0; kb < 2; ++kb)
        S[kb] = __builtin_amdgcn_mfma_f32_32x32x16_f16(af[kb], qf[db], S[kb], 0, 0, 0);
    }

    // Online softmax (exp2 domain), lane-local qrow = l31.
    // Lane holds keys kb*32 + (r&3)+8*(r>>2)+4*half; partner lane^32 has rest.
    float mx = -INFINITY;
#pragma unroll
    for (int kb = 0; kb < 2; ++kb)
#pragma unroll
      for (int r = 0; r < 16; ++r) mx = fmaxf(mx, S[kb][r]);
    mx = fmaxf(mx, __shfl_xor(mx, 32));
    float m_new = fmaxf(m_i, mx);
    float alpha = __builtin_amdgcn_exp2f(m_i - m_new);
    float s = 0.f;
#pragma unroll
    for (int kb = 0; kb < 2; ++kb)
#pragma unroll
      for (int r = 0; r < 16; ++r) {
        float p = __builtin_amdgcn_exp2f(S[kb][r] - m_new);
        S[kb][r] = p;
        s += p;
      }
    s += __shfl_xor(s, 32);
    l_i = l_i * alpha + s;
    m_i = m_new;

    // P^T -> LDS as Psh[qrow][key] (regs 4g..4g+3 are keys +0..3: pack b64)
#pragma unroll
    for (int kb = 0; kb < 2; ++kb)
#pragma unroll
      for (int rg = 0; rg < 4; ++rg) {
        f16x4 p4;
#pragma unroll
        for (int i = 0; i < 4; ++i) p4[i] = (_Float16)S[kb][rg * 4 + i];
        *(f16x4*)&Pw[l31 * 72 + kb * 32 + rg * 8 + half * 4] = p4;
      }

    // Rescale O (lane-local alpha!)
#pragma unroll
    for (int nt = 0; nt < 2; ++nt)
#pragma unroll
      for (int r = 0; r < 16; ++r) O[nt][r] *= alpha;

    // O^T += mfma(A=V^T, B=P^T): contraction over 64 keys (4 x k=16)
#pragma unroll
    for (int kb = 0; kb < 4; ++kb) {
      f16x8 pb = *(f16x8*)&Pw[l31 * 72 + kb * 16 + half * 8];
      f16x8 av[2];
#pragma unroll
      for (int nt = 0; nt < 2; ++nt) {
        int dim = nt * 32 + l31;
        int pc = ((kb * 2 + half) ^ (dim & 7)) * 8;
        av[nt] = *(f16x8*)&Vsh[dim * 64 + pc];
      }
#pragma unroll
      for (int nt = 0; nt < 2; ++nt)
        O[nt] = __builtin_amdgcn_mfma_f32_32x32x16_f16(av[nt], pb, O[nt], 0, 0, 0);
    }
  }

  // Epilogue: lane-local 1/l; O^T row = dim, col = qrow (lane-local).
  float inv = 1.f / l_i;
  int qrow = qt0 + w * 32 + l31;
#pragma unroll
  for (int nt = 0; nt < 2; ++nt)
#pragma unroll
    for (int rg = 0; rg < 4; ++rg) {
      f16x4 o4;
#pragma unroll
      for (int i = 0; i < 4; ++i) o4[i] = (_Float16)(O[nt][rg * 4 + i] * inv);
      int dim = nt * 32 + rg * 8 + half * 4;
      *(f16x4*)&y[((size_t)b * LQ + qrow) * EQ + h * 64 + dim] = o4;
    }
}

// ---------------------------------------------------------------------------
extern "C" void kernel_launch(void* const* d_in, const int* in_sizes, int n_in,
                              void* d_out, int out_size, void* d_ws, size_t ws_size,
                              hipStream_t stream) {
  const float* xt = (const float*)d_in[0];
  const float* xs = (const float*)d_in[1];
  const float* Wt = (const float*)d_in[2];
  const float* bt = (const float*)d_in[3];
  const float* Ws = (const float*)d_in[4];
  const float* bs = (const float*)d_in[5];
  const float* Wc = (const float*)d_in[6];
  const float* bc = (const float*)d_in[7];
  const float* lam_ts = (const float*)d_in[8];
  const float* lam_st = (const float*)d_in[9];
  const float* lam_ss = (const float*)d_in[10];
  float* out = (float*)d_out;

  _Float16* w16 = (_Float16*)d_ws;
  _Float16* xt16 = w16;                       // 4,194,304
  _Float16* xs16 = xt16 + 4194304;            // 4,194,304
  _Float16* WtT  = xs16 + 4194304;            // 3,145,728
  _Float16* WsT  = WtT + 3145728;             // 2,097,152
  _Float16* WcT  = WsT + 2097152;             // 1,048,576
  _Float16* qcat = WcT + 1048576;             // 8,388,608  [bh][l][128]
  _Float16* kcat = qcat + 8388608;            // 8,388,608  [bh][l][128]
  _Float16* vbufT = kcat + 8388608;           // 4,194,304  [bh][dim][l]
  _Float16* ybuf = vbufT + 4194304;           // 4,194,304  [b*l][1024]

  convert_x<<<4096, 256, 0, stream>>>(xt, xs, xt16, xs16);
  transpose_w<<<dim3(192, 32), 256, 0, stream>>>(Wt, Ws, Wc, WtT, WsT, WcT);
  gemm_bt<<<dim3(24, 32), 256, 0, stream>>>(
      xt16, WtT, bt, nullptr, qcat, kcat, vbufT, nullptr, nullptr, nullptr, 3072, 0);
  gemm_bt<<<dim3(16, 32), 256, 0, stream>>>(
      xs16, WsT, bs, nullptr, qcat, kcat, nullptr, lam_ts, lam_st, lam_ss, 2048, 1);
  flash_attn_mfma<<<dim3(16, 32), 256, 0, stream>>>(qcat, kcat, vbufT, ybuf);
  gemm_bt<<<dim3(8, 32), 256, 0, stream>>>(
      ybuf, WcT, bc, out, nullptr, nullptr, nullptr, nullptr, nullptr, nullptr, 1024, 2);
}